// Round 1
// baseline (310.996 us; speedup 1.0000x reference)
//
#include <hip/hip_runtime.h>
#include <stdint.h>

#define BATCH 8
#define NANCH 32768
#define NCLS 81
#define PRE_K 2048
#define MAX_OUT 200
#define IOU_TH 0.5f
#define SCORE_TH 0.05f

typedef uint32_t u32;
typedef uint64_t u64;

// monotone float->u32 (order-preserving for all finite floats)
__device__ __forceinline__ u32 f2sort(float f) {
  u32 u = __float_as_uint(f);
  return (u & 0x80000000u) ? ~u : (u | 0x80000000u);
}
__device__ __forceinline__ float sort2f(u32 u) {
  u = (u & 0x80000000u) ? (u & 0x7FFFFFFFu) : ~u;
  return __uint_as_float(u);
}

// ---------------- kernel 1: per-anchor max/argmax over 81 classes ----------
// one 64-lane wave per anchor; coalesced 324B read per wave
__global__ __launch_bounds__(256) void k_score(const float* __restrict__ confs,
                                               u64* __restrict__ keys,
                                               int* __restrict__ cats) {
  int ga = blockIdx.x * 4 + (threadIdx.x >> 6);  // global anchor index b*N+n
  int lane = threadIdx.x & 63;
  const float* p = confs + (size_t)ga * NCLS;
  float v = p[lane];
  int ci = lane;
  if (lane < NCLS - 64) {  // classes 64..80
    float v2 = p[64 + lane];
    if (v2 > v) { v = v2; ci = 64 + lane; }  // strict > keeps first-index on tie
  }
  // butterfly reduce: max value, first (smallest) index on ties
  #pragma unroll
  for (int off = 32; off; off >>= 1) {
    float ov = __shfl_xor(v, off);
    int oi = __shfl_xor(ci, off);
    if (ov > v || (ov == v && oi < ci)) { v = ov; ci = oi; }
  }
  if (lane == 0) {
    int n = ga & (NANCH - 1);
    bool valid = (v > SCORE_TH) && (ci != 0);
    float s = valid ? v : -1.0f;
    // distinct key: score desc, index asc on tie
    keys[ga] = ((u64)f2sort(s) << 32) | (u64)(0xFFFFFFFFu - (u32)n);
    cats[ga] = ci;
  }
}

// ---------------- kernel 2: per-batch exact top-2048 (radix select + sort) --
__global__ __launch_bounds__(1024) void k_select(const u64* __restrict__ keys,
                                                 const int* __restrict__ cats,
                                                 const float* __restrict__ boxes,
                                                 float4* __restrict__ candOff,
                                                 float4* __restrict__ candOrig,
                                                 float* __restrict__ candScore,
                                                 int* __restrict__ candCat) {
  int b = blockIdx.x;
  int tid = threadIdx.x;
  const u64* bk = keys + (size_t)b * NANCH;

  __shared__ u32 hist[256];
  __shared__ u64 sh_prefix;
  __shared__ int sh_need;
  __shared__ u64 skeys[PRE_K];
  __shared__ int scnt;

  if (tid == 0) { sh_prefix = 0; sh_need = PRE_K; }
  __syncthreads();

  // MSB-first radix select: find exact 2048th-largest u64 key
  for (int pass = 0; pass < 8; ++pass) {
    if (tid < 256) hist[tid] = 0;
    __syncthreads();
    u64 pfx = sh_prefix;
    int shift = 56 - 8 * pass;
    for (int idx = tid; idx < NANCH; idx += 1024) {
      u64 k = bk[idx];
      if (pass == 0 || (k >> (shift + 8)) == pfx)
        atomicAdd(&hist[(u32)((k >> shift) & 0xFF)], 1u);
    }
    __syncthreads();
    if (tid == 0) {
      int need = sh_need;
      int acc = 0;
      int d = 255;
      for (; d >= 0; --d) {
        acc += (int)hist[d];
        if (acc >= need) break;
      }
      if (d < 0) d = 0;  // defensive; cannot happen (invariant: matches >= need)
      sh_need = need - (acc - (int)hist[d]);
      sh_prefix = (pfx << 8) | (u64)d;
    }
    __syncthreads();
  }
  u64 T = sh_prefix;  // the 2048th-largest key; keys distinct -> exactly 2048 >= T

  if (tid == 0) scnt = 0;
  __syncthreads();
  for (int idx = tid; idx < NANCH; idx += 1024) {
    u64 k = bk[idx];
    if (k >= T) {
      int pos = atomicAdd(&scnt, 1);
      if (pos < PRE_K) skeys[pos] = k;
    }
  }
  __syncthreads();

  // bitonic sort ascending over 2048 keys in LDS
  for (int k = 2; k <= PRE_K; k <<= 1) {
    for (int j = k >> 1; j > 0; j >>= 1) {
      for (int idx = tid; idx < PRE_K; idx += 1024) {
        int ixj = idx ^ j;
        if (ixj > idx) {
          u64 a = skeys[idx], c = skeys[ixj];
          bool up = ((idx & k) == 0);
          if ((a > c) == up) { skeys[idx] = c; skeys[ixj] = a; }
        }
      }
      __syncthreads();
    }
  }

  // emit rank-ordered candidates (rank r = descending score = skeys[PRE_K-1-r])
  for (int r = tid; r < PRE_K; r += 1024) {
    u64 k = skeys[PRE_K - 1 - r];
    u32 n = 0xFFFFFFFFu - (u32)(k & 0xFFFFFFFFu);
    float s = sort2f((u32)(k >> 32));
    int cat = cats[(size_t)b * NANCH + n];
    const float* bp = boxes + ((size_t)b * NANCH + n) * 4;
    float4 ob = make_float4(bp[0], bp[1], bp[2], bp[3]);
    float off = 2.0f * (float)cat;
    // reference computes IoU on offset boxes (with f32 rounding of the add)
    float4 obo = make_float4(ob.x + off, ob.y + off, ob.z + off, ob.w + off);
    int o = b * PRE_K + r;
    candOff[o] = obo;
    candOrig[o] = ob;
    candScore[o] = s;
    candCat[o] = cat;
  }
}

// ---------------- kernel 3: 2048x2048 suppression bitmask -------------------
// grid (PRE_K/16, BATCH), 512 threads: each thread = 1 row x 64-col word
__global__ __launch_bounds__(512) void k_mask(const float4* __restrict__ candOff,
                                              u64* __restrict__ mask) {
  int b = blockIdx.y;
  int rowBase = blockIdx.x * 16;
  int tid = threadIdx.x;
  __shared__ float4 sb[PRE_K];  // 32 KB
  for (int j = tid; j < PRE_K; j += 512) sb[j] = candOff[b * PRE_K + j];
  __syncthreads();
  int i = rowBase + (tid >> 5);
  int w = tid & 31;
  float4 bi = sb[i];
  float areai = fmaxf(bi.z - bi.x, 0.0f) * fmaxf(bi.w - bi.y, 0.0f);
  u64 word = 0;
  int j0 = w * 64;
  #pragma unroll 4
  for (int jj = 0; jj < 64; ++jj) {
    float4 bj = sb[j0 + jj];
    float lx = fmaxf(bi.x, bj.x), ly = fmaxf(bi.y, bj.y);
    float rx = fminf(bi.z, bj.z), ry = fminf(bi.w, bj.w);
    float iw = fmaxf(rx - lx, 0.0f), ih = fmaxf(ry - ly, 0.0f);
    float inter = iw * ih;
    float areaj = fmaxf(bj.z - bj.x, 0.0f) * fmaxf(bj.w - bj.y, 0.0f);
    float uni = areai + areaj - inter;
    float iou = inter / fmaxf(uni, 1e-9f);
    if (iou > IOU_TH) word |= (1ull << jj);
  }
  mask[((size_t)(b * PRE_K + i)) * 32 + w] = word;
}

// ---------------- kernel 4: greedy scan (bitmask) + output ------------------
// one wave per batch; remv bitmask in 32 lane-registers; early exit at 200 kept
__global__ __launch_bounds__(64) void k_scan(const u64* __restrict__ mask,
                                             const float4* __restrict__ candOrig,
                                             const float* __restrict__ candScore,
                                             const int* __restrict__ candCat,
                                             float* __restrict__ out) {
  int b = blockIdx.x;
  int tid = threadIdx.x;
  __shared__ float ssc[PRE_K];
  __shared__ int keptI[MAX_OUT];
  for (int j = tid; j < PRE_K; j += 64) ssc[j] = candScore[b * PRE_K + j];
  __syncthreads();

  const u64* mrow = mask + (size_t)b * PRE_K * 32;
  int wsel = tid & 31;
  u64 remv = 0;
  int cnt = 0;
  u64 rowCur = mrow[wsel];  // prefetch row 0
  for (int i = 0; i < PRE_K && cnt < MAX_OUT; ++i) {
    u64 rowNxt = (i + 1 < PRE_K) ? mrow[(size_t)(i + 1) * 32 + wsel] : 0ull;
    u64 wbits = __shfl(remv, i >> 6);      // word holding bit i (lane i>>6 < 32)
    bool sup = (wbits >> (i & 63)) & 1ull;
    if (!sup && ssc[i] > SCORE_TH) {       // uniform branch
      if (tid == 0) keptI[cnt] = i;
      if (tid < 32) remv |= rowCur;
      cnt++;
    }
    rowCur = rowNxt;
  }
  __syncthreads();

  float* out5 = out;                          // [B][200][5]
  float* ocat = out + BATCH * MAX_OUT * 5;    // [B][200] (cats as float)
  for (int r = tid; r < MAX_OUT; r += 64) {
    float* p = out5 + ((size_t)(b * MAX_OUT + r)) * 5;
    if (r < cnt) {
      int i = keptI[r];
      float4 ob = candOrig[b * PRE_K + i];
      p[0] = ob.x; p[1] = ob.y; p[2] = ob.z; p[3] = ob.w; p[4] = ssc[i];
      ocat[b * MAX_OUT + r] = (float)candCat[b * PRE_K + i];
    } else {
      p[0] = 0.0f; p[1] = 0.0f; p[2] = 0.0f; p[3] = 0.0f; p[4] = 0.0f;
      ocat[b * MAX_OUT + r] = 0.0f;
    }
  }
}

extern "C" void kernel_launch(void* const* d_in, const int* in_sizes, int n_in,
                              void* d_out, int out_size, void* d_ws, size_t ws_size,
                              hipStream_t stream) {
  const float* boxes = (const float*)d_in[0];  // [8,32768,4]
  const float* confs = (const float*)d_in[1];  // [8,32768,81]
  float* out = (float*)d_out;                  // 8000 floats + 1600 cat-as-float
  char* ws = (char*)d_ws;

  // workspace layout (~8 MB total)
  u64* keys      = (u64*)(ws);                              // 2 MB
  int* cats      = (int*)(ws + (2u << 20));                 // 1 MB
  float4* cOff   = (float4*)(ws + (3u << 20));              // 256 KB
  float4* cOrig  = (float4*)(ws + (3u << 20) + (256u << 10));
  float* cScore  = (float*)(ws + (3u << 20) + (512u << 10));
  int* cCat      = (int*)(ws + (3u << 20) + (576u << 10));
  u64* mask      = (u64*)(ws + (4u << 20));                 // 4 MB

  k_score<<<BATCH * NANCH / 4, 256, 0, stream>>>(confs, keys, cats);
  k_select<<<BATCH, 1024, 0, stream>>>(keys, cats, boxes, cOff, cOrig, cScore, cCat);
  dim3 g3(PRE_K / 16, BATCH);
  k_mask<<<g3, 512, 0, stream>>>(cOff, mask);
  k_scan<<<BATCH, 64, 0, stream>>>(mask, cOrig, cScore, cCat, out);
}

// Round 2
// 282.195 us; speedup vs baseline: 1.1021x; 1.1021x over previous
//
#include <hip/hip_runtime.h>
#include <stdint.h>

#define BATCH 8
#define NANCH 32768
#define NCLS 81
#define PRE_K 2048
#define MAX_OUT 200
#define IOU_TH 0.5f
#define SCORE_TH 0.05f

typedef uint32_t u32;
typedef uint64_t u64;
typedef uint8_t u8;

// monotone float->u32 (order-preserving)
__device__ __forceinline__ u32 f2sort(float f) {
  u32 u = __float_as_uint(f);
  return (u & 0x80000000u) ? ~u : (u | 0x80000000u);
}
__device__ __forceinline__ float sort2f(u32 u) {
  u = (u & 0x80000000u) ? (u & 0x7FFFFFFFu) : ~u;
  return __uint_as_float(u);
}

// ---------------- kernel 1: per-anchor max/argmax over 81 classes ----------
__global__ __launch_bounds__(256) void k_score(const float* __restrict__ confs,
                                               u64* __restrict__ keys,
                                               u8* __restrict__ cats) {
  int ga = blockIdx.x * 4 + (threadIdx.x >> 6);
  int lane = threadIdx.x & 63;
  const float* p = confs + (size_t)ga * NCLS;
  float v = p[lane];
  int ci = lane;
  if (lane < NCLS - 64) {
    float v2 = p[64 + lane];
    if (v2 > v) { v = v2; ci = 64 + lane; }
  }
  #pragma unroll
  for (int off = 32; off; off >>= 1) {
    float ov = __shfl_xor(v, off);
    int oi = __shfl_xor(ci, off);
    if (ov > v || (ov == v && oi < ci)) { v = ov; ci = oi; }
  }
  if (lane == 0) {
    int n = ga & (NANCH - 1);
    bool valid = (v > SCORE_TH) && (ci != 0);
    float s = valid ? v : -1.0f;
    keys[ga] = ((u64)f2sort(s) << 32) | (u64)(0xFFFFFFFFu - (u32)n);
    cats[ga] = (u8)ci;
  }
}

// ------------- digit-threshold scan helper (redundant per WG) --------------
// hist gh[B]; find digit D (from top) s.t. suffix_count(D) >= need >
// suffix_count(D+1); returns D and new need. sbuf: shared u32[258].
template <int B>
__device__ void scan_digit(const u32* __restrict__ gh, int need, u32* sbuf,
                           int tid, int* D, int* NO) {
  const int CS = B / 256;
  u32 psum = 0;
  if (tid < 256) {
    int hi = B - 1 - tid * CS;
    #pragma unroll 4
    for (int k2 = 0; k2 < CS; ++k2) psum += gh[hi - k2];
    sbuf[tid] = psum;
  }
  __syncthreads();
  for (int off = 1; off < 256; off <<= 1) {
    u32 v = 0;
    if (tid < 256 && tid >= off) v = sbuf[tid - off];
    __syncthreads();
    if (tid < 256) sbuf[tid] += v;
    __syncthreads();
  }
  if (tid < 256) {
    u32 inc = sbuf[tid], exc = inc - psum;
    if (inc >= (u32)need && exc < (u32)need) {  // unique boundary chunk
      int acc = (int)exc, hi = B - 1 - tid * CS, d = hi, no = 0;
      for (int k2 = 0; k2 < CS; ++k2) {
        d = hi - k2;
        u32 h = gh[d];
        acc += (int)h;
        if (acc >= need) { no = need - (acc - (int)h); break; }
      }
      sbuf[256] = (u32)d;
      sbuf[257] = (u32)no;
    }
  }
  __syncthreads();
  *D = (int)sbuf[256];
  *NO = (int)sbuf[257];
  __syncthreads();
}

// ---------------- histogram passes (grid-parallel, 4 WGs/batch) ------------
__global__ __launch_bounds__(1024) void k_hist1(const u64* __restrict__ keys,
                                                u32* __restrict__ h1) {
  int b = blockIdx.x >> 2, sub = blockIdx.x & 3;
  __shared__ u32 lh[256];
  for (int i = threadIdx.x; i < 256; i += 1024) lh[i] = 0;
  __syncthreads();
  const u64* bk = keys + (size_t)b * NANCH;
  int base = sub * 8192;
  for (int i = base + threadIdx.x; i < base + 8192; i += 1024) {
    u32 k32 = (u32)(bk[i] >> 32);
    atomicAdd(&lh[k32 >> 24], 1u);
  }
  __syncthreads();
  for (int i = threadIdx.x; i < 256; i += 1024) {
    u32 v = lh[i];
    if (v) atomicAdd(&h1[b * 256 + i], v);
  }
}

__global__ __launch_bounds__(1024) void k_hist2(const u64* __restrict__ keys,
                                                const u32* __restrict__ h1,
                                                u32* __restrict__ h2) {
  int b = blockIdx.x >> 2, sub = blockIdx.x & 3;
  __shared__ u32 sbuf[258];
  __shared__ u32 lh[2048];
  int D1, n1;
  scan_digit<256>(h1 + b * 256, PRE_K, sbuf, threadIdx.x, &D1, &n1);
  for (int i = threadIdx.x; i < 2048; i += 1024) lh[i] = 0;
  __syncthreads();
  const u64* bk = keys + (size_t)b * NANCH;
  int base = sub * 8192;
  for (int i = base + threadIdx.x; i < base + 8192; i += 1024) {
    u32 k32 = (u32)(bk[i] >> 32);
    if ((int)(k32 >> 24) == D1) atomicAdd(&lh[(k32 >> 13) & 0x7FF], 1u);
  }
  __syncthreads();
  for (int i = threadIdx.x; i < 2048; i += 1024) {
    u32 v = lh[i];
    if (v) atomicAdd(&h2[b * 2048 + i], v);
  }
}

__global__ __launch_bounds__(1024) void k_hist3(const u64* __restrict__ keys,
                                                const u32* __restrict__ h1,
                                                const u32* __restrict__ h2,
                                                u32* __restrict__ h3) {
  int b = blockIdx.x >> 2, sub = blockIdx.x & 3;
  __shared__ u32 sbuf[258];
  __shared__ u32 lh[8192];  // 32 KB
  int D1, n1, D2, n2;
  scan_digit<256>(h1 + b * 256, PRE_K, sbuf, threadIdx.x, &D1, &n1);
  scan_digit<2048>(h2 + b * 2048, n1, sbuf, threadIdx.x, &D2, &n2);
  for (int i = threadIdx.x; i < 8192; i += 1024) lh[i] = 0;
  __syncthreads();
  const u64* bk = keys + (size_t)b * NANCH;
  int base = sub * 8192;
  for (int i = base + threadIdx.x; i < base + 8192; i += 1024) {
    u32 k32 = (u32)(bk[i] >> 32);
    if ((int)(k32 >> 24) == D1 && (int)((k32 >> 13) & 0x7FF) == D2)
      atomicAdd(&lh[k32 & 0x1FFF], 1u);
  }
  __syncthreads();
  for (int i = threadIdx.x; i < 8192; i += 1024) {
    u32 v = lh[i];
    if (v) atomicAdd(&h3[b * 8192 + i], v);
  }
}

// ---------------- compaction: strict-greater + boundary ties ---------------
__global__ __launch_bounds__(1024) void k_compact(const u64* __restrict__ keys,
                                                  const u32* __restrict__ h1,
                                                  const u32* __restrict__ h2,
                                                  const u32* __restrict__ h3,
                                                  u64* __restrict__ selKey,
                                                  u64* __restrict__ tieKey,
                                                  u32* __restrict__ cntSel,
                                                  u32* __restrict__ cntTie,
                                                  u32* __restrict__ gNeed3) {
  int b = blockIdx.x >> 2, sub = blockIdx.x & 3;
  __shared__ u32 sbuf[258];
  int D1, n1, D2, n2, D3, n3;
  scan_digit<256>(h1 + b * 256, PRE_K, sbuf, threadIdx.x, &D1, &n1);
  scan_digit<2048>(h2 + b * 2048, n1, sbuf, threadIdx.x, &D2, &n2);
  scan_digit<8192>(h3 + b * 8192, n2, sbuf, threadIdx.x, &D3, &n3);
  u32 S32 = ((u32)D1 << 24) | ((u32)D2 << 13) | (u32)D3;
  if (threadIdx.x == 0 && sub == 0) gNeed3[b] = (u32)n3;
  const u64* bk = keys + (size_t)b * NANCH;
  int base = sub * 8192;
  for (int i = base + threadIdx.x; i < base + 8192; i += 1024) {
    u64 k = bk[i];
    u32 k32 = (u32)(k >> 32);
    if (k32 > S32) {
      u32 pos = atomicAdd(&cntSel[b], 1u);
      selKey[b * PRE_K + pos] = k;
    } else if (k32 == S32) {
      u32 pos = atomicAdd(&cntTie[b], 1u);
      if (pos < 128) tieKey[b * 128 + pos] = k;
    }
  }
}

// resolve boundary ties: take need3 largest keys (== smallest anchor index)
__global__ __launch_bounds__(256) void k_resolve(u64* __restrict__ selKey,
                                                 const u64* __restrict__ tieKey,
                                                 const u32* __restrict__ cntSel,
                                                 const u32* __restrict__ cntTie,
                                                 const u32* __restrict__ gNeed3) {
  int b = blockIdx.x;
  int nt = (int)cntTie[b];
  if (nt > 128) nt = 128;
  int need3 = (int)gNeed3[b];
  int cgt = (int)cntSel[b];
  int t = threadIdx.x;
  if (t < nt) {
    u64 my = tieKey[b * 128 + t];
    int r = 0;
    for (int j = 0; j < nt; ++j) r += (tieKey[b * 128 + j] > my);
    if (r < need3) selKey[b * PRE_K + cgt + r] = my;
  }
}

// ---------------- rank-by-count ordering + candidate record emit -----------
__global__ __launch_bounds__(512) void k_rank(const u64* __restrict__ selKey,
                                              const u8* __restrict__ cats,
                                              const float* __restrict__ boxes,
                                              float4* __restrict__ candOff,
                                              float4* __restrict__ candOrig,
                                              float* __restrict__ candScore,
                                              int* __restrict__ candCat) {
  int b = blockIdx.y;
  int tid = threadIdx.x;
  __shared__ u64 sk[PRE_K];  // 16 KB
  for (int i = tid; i < PRE_K; i += 512) sk[i] = selKey[b * PRE_K + i];
  __syncthreads();
  int me = blockIdx.x * 512 + tid;
  u64 my = sk[me];
  int rank = 0;
  #pragma unroll 8
  for (int j = 0; j < PRE_K; ++j) rank += (sk[j] > my);  // LDS broadcast reads
  u32 n = 0xFFFFFFFFu - (u32)(my & 0xFFFFFFFFu);
  float s = sort2f((u32)(my >> 32));
  int cat = (int)cats[(size_t)b * NANCH + n];
  const float* bp = boxes + ((size_t)b * NANCH + n) * 4;
  float4 ob = make_float4(bp[0], bp[1], bp[2], bp[3]);
  float off = 2.0f * (float)cat;
  float4 obo = make_float4(ob.x + off, ob.y + off, ob.z + off, ob.w + off);
  int o = b * PRE_K + rank;
  candOff[o] = obo;
  candOrig[o] = ob;
  candScore[o] = s;
  candCat[o] = cat;
}

// ---------------- 2048x2048 suppression bitmask ----------------------------
__global__ __launch_bounds__(512) void k_mask(const float4* __restrict__ candOff,
                                              u64* __restrict__ mask) {
  int b = blockIdx.y;
  int rowBase = blockIdx.x * 16;
  int tid = threadIdx.x;
  __shared__ float4 sb[PRE_K];  // 32 KB
  for (int j = tid; j < PRE_K; j += 512) sb[j] = candOff[b * PRE_K + j];
  __syncthreads();
  int i = rowBase + (tid >> 5);
  int w = tid & 31;
  float4 bi = sb[i];
  float areai = fmaxf(bi.z - bi.x, 0.0f) * fmaxf(bi.w - bi.y, 0.0f);
  u64 word = 0;
  int j0 = w * 64;
  #pragma unroll 4
  for (int jj = 0; jj < 64; ++jj) {
    float4 bj = sb[j0 + jj];
    float lx = fmaxf(bi.x, bj.x), ly = fmaxf(bi.y, bj.y);
    float rx = fminf(bi.z, bj.z), ry = fminf(bi.w, bj.w);
    float iw = fmaxf(rx - lx, 0.0f), ih = fmaxf(ry - ly, 0.0f);
    float inter = iw * ih;
    float areaj = fmaxf(bj.z - bj.x, 0.0f) * fmaxf(bj.w - bj.y, 0.0f);
    float uni = areai + areaj - inter;
    float iou = inter / fmaxf(uni, 1e-9f);
    if (iou > IOU_TH) word |= (1ull << jj);
  }
  mask[((size_t)(b * PRE_K + i)) * 32 + w] = word;
}

// ---------------- greedy scan + output -------------------------------------
__global__ __launch_bounds__(64) void k_scan(const u64* __restrict__ mask,
                                             const float4* __restrict__ candOrig,
                                             const float* __restrict__ candScore,
                                             const int* __restrict__ candCat,
                                             float* __restrict__ out) {
  int b = blockIdx.x;
  int tid = threadIdx.x;
  __shared__ float ssc[PRE_K];
  __shared__ int keptI[MAX_OUT];
  for (int j = tid; j < PRE_K; j += 64) ssc[j] = candScore[b * PRE_K + j];
  __syncthreads();

  const u64* mrow = mask + (size_t)b * PRE_K * 32;
  int wsel = tid & 31;
  u64 remv = 0;
  int cnt = 0;
  u64 rowCur = mrow[wsel];
  for (int i = 0; i < PRE_K && cnt < MAX_OUT; ++i) {
    u64 rowNxt = (i + 1 < PRE_K) ? mrow[(size_t)(i + 1) * 32 + wsel] : 0ull;
    u64 wbits = __shfl(remv, i >> 6);
    bool sup = (wbits >> (i & 63)) & 1ull;
    if (!sup && ssc[i] > SCORE_TH) {
      if (tid == 0) keptI[cnt] = i;
      if (tid < 32) remv |= rowCur;
      cnt++;
    }
    rowCur = rowNxt;
  }
  __syncthreads();

  float* out5 = out;
  float* ocat = out + BATCH * MAX_OUT * 5;
  for (int r = tid; r < MAX_OUT; r += 64) {
    float* p = out5 + ((size_t)(b * MAX_OUT + r)) * 5;
    if (r < cnt) {
      int i = keptI[r];
      float4 ob = candOrig[b * PRE_K + i];
      p[0] = ob.x; p[1] = ob.y; p[2] = ob.z; p[3] = ob.w; p[4] = ssc[i];
      ocat[b * MAX_OUT + r] = (float)candCat[b * PRE_K + i];
    } else {
      p[0] = 0.0f; p[1] = 0.0f; p[2] = 0.0f; p[3] = 0.0f; p[4] = 0.0f;
      ocat[b * MAX_OUT + r] = 0.0f;
    }
  }
}

extern "C" void kernel_launch(void* const* d_in, const int* in_sizes, int n_in,
                              void* d_out, int out_size, void* d_ws, size_t ws_size,
                              hipStream_t stream) {
  const float* boxes = (const float*)d_in[0];
  const float* confs = (const float*)d_in[1];
  float* out = (float*)d_out;
  char* ws = (char*)d_ws;

  // workspace layout (<= 8 MB)
  const size_t OFF_KEYS = 0;                            // 2 MB
  const size_t OFF_CATS = (size_t)2 << 20;              // 256 KB (u8)
  const size_t OFF_H1   = OFF_CATS + (256u << 10);      // 8 KB
  const size_t OFF_H2   = OFF_H1 + 8 * 256 * 4;         // 64 KB
  const size_t OFF_H3   = OFF_H2 + 8 * 2048 * 4;        // 256 KB
  const size_t OFF_CNT  = OFF_H3 + 8 * 8192 * 4;        // 1 KB (cntSel/cntTie/gNeed3)
  const size_t OFF_SELK = OFF_CNT + 1024;               // 128 KB
  const size_t OFF_TIE  = OFF_SELK + 8 * PRE_K * 8;     // 8 KB
  const size_t OFF_COFF = OFF_TIE + 8 * 128 * 8;        // 256 KB
  const size_t OFF_CORG = OFF_COFF + (256u << 10);      // 256 KB
  const size_t OFF_CSC  = OFF_CORG + (256u << 10);      // 64 KB
  const size_t OFF_CCAT = OFF_CSC + (64u << 10);        // 64 KB
  const size_t OFF_MASK = OFF_CCAT + (64u << 10);       // 4 MB

  u64* keys    = (u64*)(ws + OFF_KEYS);
  u8* cats     = (u8*)(ws + OFF_CATS);
  u32* h1      = (u32*)(ws + OFF_H1);
  u32* h2      = (u32*)(ws + OFF_H2);
  u32* h3      = (u32*)(ws + OFF_H3);
  u32* cntSel  = (u32*)(ws + OFF_CNT);
  u32* cntTie  = (u32*)(ws + OFF_CNT + 64);
  u32* gNeed3  = (u32*)(ws + OFF_CNT + 128);
  u64* selKey  = (u64*)(ws + OFF_SELK);
  u64* tieKey  = (u64*)(ws + OFF_TIE);
  float4* cOff = (float4*)(ws + OFF_COFF);
  float4* cOrg = (float4*)(ws + OFF_CORG);
  float* cSc   = (float*)(ws + OFF_CSC);
  int* cCat    = (int*)(ws + OFF_CCAT);
  u64* mask    = (u64*)(ws + OFF_MASK);

  // zero hists + counters (h1..cnt block is contiguous)
  hipMemsetAsync(ws + OFF_H1, 0, (OFF_CNT + 1024) - OFF_H1, stream);

  k_score<<<BATCH * NANCH / 4, 256, 0, stream>>>(confs, keys, cats);
  k_hist1<<<32, 1024, 0, stream>>>(keys, h1);
  k_hist2<<<32, 1024, 0, stream>>>(keys, h1, h2);
  k_hist3<<<32, 1024, 0, stream>>>(keys, h1, h2, h3);
  k_compact<<<32, 1024, 0, stream>>>(keys, h1, h2, h3, selKey, tieKey, cntSel, cntTie, gNeed3);
  k_resolve<<<BATCH, 256, 0, stream>>>(selKey, tieKey, cntSel, cntTie, gNeed3);
  dim3 gr(PRE_K / 512, BATCH);
  k_rank<<<gr, 512, 0, stream>>>(selKey, cats, boxes, cOff, cOrg, cSc, cCat);
  dim3 g3(PRE_K / 16, BATCH);
  k_mask<<<g3, 512, 0, stream>>>(cOff, mask);
  k_scan<<<BATCH, 64, 0, stream>>>(mask, cOrg, cSc, cCat, out);
}

// Round 3
// 241.042 us; speedup vs baseline: 1.2902x; 1.1707x over previous
//
#include <hip/hip_runtime.h>
#include <stdint.h>

#define BATCH 8
#define NANCH 32768
#define NCLS 81
#define PRE_K 2048
#define MAX_OUT 200
#define IOU_TH 0.5f
#define SCORE_TH 0.05f

typedef uint32_t u32;
typedef uint64_t u64;
typedef uint8_t u8;

// monotone float->u32 (order-preserving)
__device__ __forceinline__ u32 f2sort(float f) {
  u32 u = __float_as_uint(f);
  return (u & 0x80000000u) ? ~u : (u | 0x80000000u);
}
__device__ __forceinline__ float sort2f(u32 u) {
  u = (u & 0x80000000u) ? (u & 0x7FFFFFFFu) : ~u;
  return __uint_as_float(u);
}

// ---------------- kernel 1: per-anchor max/argmax over 81 classes ----------
__global__ __launch_bounds__(256) void k_score(const float* __restrict__ confs,
                                               u64* __restrict__ keys,
                                               u8* __restrict__ cats) {
  int ga = blockIdx.x * 4 + (threadIdx.x >> 6);
  int lane = threadIdx.x & 63;
  const float* p = confs + (size_t)ga * NCLS;
  float v = p[lane];
  int ci = lane;
  if (lane < NCLS - 64) {
    float v2 = p[64 + lane];
    if (v2 > v) { v = v2; ci = 64 + lane; }
  }
  #pragma unroll
  for (int off = 32; off; off >>= 1) {
    float ov = __shfl_xor(v, off);
    int oi = __shfl_xor(ci, off);
    if (ov > v || (ov == v && oi < ci)) { v = ov; ci = oi; }
  }
  if (lane == 0) {
    int n = ga & (NANCH - 1);
    bool valid = (v > SCORE_TH) && (ci != 0);
    float s = valid ? v : -1.0f;
    keys[ga] = ((u64)f2sort(s) << 32) | (u64)(0xFFFFFFFFu - (u32)n);
    cats[ga] = (u8)ci;
  }
}

// ------------- digit-threshold scan helper (redundant per WG) --------------
template <int B>
__device__ void scan_digit(const u32* __restrict__ gh, int need, u32* sbuf,
                           int tid, int* D, int* NO) {
  const int CS = B / 256;
  u32 psum = 0;
  if (tid < 256) {
    int hi = B - 1 - tid * CS;
    #pragma unroll 4
    for (int k2 = 0; k2 < CS; ++k2) psum += gh[hi - k2];
    sbuf[tid] = psum;
  }
  __syncthreads();
  for (int off = 1; off < 256; off <<= 1) {
    u32 v = 0;
    if (tid < 256 && tid >= off) v = sbuf[tid - off];
    __syncthreads();
    if (tid < 256) sbuf[tid] += v;
    __syncthreads();
  }
  if (tid < 256) {
    u32 inc = sbuf[tid], exc = inc - psum;
    if (inc >= (u32)need && exc < (u32)need) {
      int acc = (int)exc, hi = B - 1 - tid * CS, d = hi, no = 0;
      for (int k2 = 0; k2 < CS; ++k2) {
        d = hi - k2;
        u32 h = gh[d];
        acc += (int)h;
        if (acc >= need) { no = need - (acc - (int)h); break; }
      }
      sbuf[256] = (u32)d;
      sbuf[257] = (u32)no;
    }
  }
  __syncthreads();
  *D = (int)sbuf[256];
  *NO = (int)sbuf[257];
  __syncthreads();
}

// ---------------- histogram passes (grid-parallel, 4 WGs/batch) ------------
__global__ __launch_bounds__(1024) void k_hist1(const u64* __restrict__ keys,
                                                u32* __restrict__ h1) {
  int b = blockIdx.x >> 2, sub = blockIdx.x & 3;
  __shared__ u32 lh[256];
  for (int i = threadIdx.x; i < 256; i += 1024) lh[i] = 0;
  __syncthreads();
  const u64* bk = keys + (size_t)b * NANCH;
  int base = sub * 8192;
  for (int i = base + threadIdx.x; i < base + 8192; i += 1024) {
    u32 k32 = (u32)(bk[i] >> 32);
    atomicAdd(&lh[k32 >> 24], 1u);
  }
  __syncthreads();
  for (int i = threadIdx.x; i < 256; i += 1024) {
    u32 v = lh[i];
    if (v) atomicAdd(&h1[b * 256 + i], v);
  }
}

__global__ __launch_bounds__(1024) void k_hist2(const u64* __restrict__ keys,
                                                const u32* __restrict__ h1,
                                                u32* __restrict__ h2) {
  int b = blockIdx.x >> 2, sub = blockIdx.x & 3;
  __shared__ u32 sbuf[258];
  __shared__ u32 lh[2048];
  int D1, n1;
  scan_digit<256>(h1 + b * 256, PRE_K, sbuf, threadIdx.x, &D1, &n1);
  for (int i = threadIdx.x; i < 2048; i += 1024) lh[i] = 0;
  __syncthreads();
  const u64* bk = keys + (size_t)b * NANCH;
  int base = sub * 8192;
  for (int i = base + threadIdx.x; i < base + 8192; i += 1024) {
    u32 k32 = (u32)(bk[i] >> 32);
    if ((int)(k32 >> 24) == D1) atomicAdd(&lh[(k32 >> 13) & 0x7FF], 1u);
  }
  __syncthreads();
  for (int i = threadIdx.x; i < 2048; i += 1024) {
    u32 v = lh[i];
    if (v) atomicAdd(&h2[b * 2048 + i], v);
  }
}

__global__ __launch_bounds__(1024) void k_hist3(const u64* __restrict__ keys,
                                                const u32* __restrict__ h1,
                                                const u32* __restrict__ h2,
                                                u32* __restrict__ h3) {
  int b = blockIdx.x >> 2, sub = blockIdx.x & 3;
  __shared__ u32 sbuf[258];
  __shared__ u32 lh[8192];  // 32 KB
  int D1, n1, D2, n2;
  scan_digit<256>(h1 + b * 256, PRE_K, sbuf, threadIdx.x, &D1, &n1);
  scan_digit<2048>(h2 + b * 2048, n1, sbuf, threadIdx.x, &D2, &n2);
  for (int i = threadIdx.x; i < 8192; i += 1024) lh[i] = 0;
  __syncthreads();
  const u64* bk = keys + (size_t)b * NANCH;
  int base = sub * 8192;
  for (int i = base + threadIdx.x; i < base + 8192; i += 1024) {
    u32 k32 = (u32)(bk[i] >> 32);
    if ((int)(k32 >> 24) == D1 && (int)((k32 >> 13) & 0x7FF) == D2)
      atomicAdd(&lh[k32 & 0x1FFF], 1u);
  }
  __syncthreads();
  for (int i = threadIdx.x; i < 8192; i += 1024) {
    u32 v = lh[i];
    if (v) atomicAdd(&h3[b * 8192 + i], v);
  }
}

// ---------------- compaction: strict-greater + boundary ties ---------------
__global__ __launch_bounds__(1024) void k_compact(const u64* __restrict__ keys,
                                                  const u32* __restrict__ h1,
                                                  const u32* __restrict__ h2,
                                                  const u32* __restrict__ h3,
                                                  u64* __restrict__ selKey,
                                                  u64* __restrict__ tieKey,
                                                  u32* __restrict__ cntSel,
                                                  u32* __restrict__ cntTie,
                                                  u32* __restrict__ gNeed3) {
  int b = blockIdx.x >> 2, sub = blockIdx.x & 3;
  __shared__ u32 sbuf[258];
  int D1, n1, D2, n2, D3, n3;
  scan_digit<256>(h1 + b * 256, PRE_K, sbuf, threadIdx.x, &D1, &n1);
  scan_digit<2048>(h2 + b * 2048, n1, sbuf, threadIdx.x, &D2, &n2);
  scan_digit<8192>(h3 + b * 8192, n2, sbuf, threadIdx.x, &D3, &n3);
  u32 S32 = ((u32)D1 << 24) | ((u32)D2 << 13) | (u32)D3;
  if (threadIdx.x == 0 && sub == 0) gNeed3[b] = (u32)n3;
  const u64* bk = keys + (size_t)b * NANCH;
  int base = sub * 8192;
  for (int i = base + threadIdx.x; i < base + 8192; i += 1024) {
    u64 k = bk[i];
    u32 k32 = (u32)(k >> 32);
    if (k32 > S32) {
      u32 pos = atomicAdd(&cntSel[b], 1u);
      selKey[b * PRE_K + pos] = k;
    } else if (k32 == S32) {
      u32 pos = atomicAdd(&cntTie[b], 1u);
      if (pos < 128) tieKey[b * 128 + pos] = k;
    }
  }
}

// resolve boundary ties: take need3 largest keys (== smallest anchor index)
__global__ __launch_bounds__(256) void k_resolve(u64* __restrict__ selKey,
                                                 const u64* __restrict__ tieKey,
                                                 const u32* __restrict__ cntSel,
                                                 const u32* __restrict__ cntTie,
                                                 const u32* __restrict__ gNeed3) {
  int b = blockIdx.x;
  int nt = (int)cntTie[b];
  if (nt > 128) nt = 128;
  int need3 = (int)gNeed3[b];
  int cgt = (int)cntSel[b];
  int t = threadIdx.x;
  if (t < nt) {
    u64 my = tieKey[b * 128 + t];
    int r = 0;
    for (int j = 0; j < nt; ++j) r += (tieKey[b * 128 + j] > my);
    if (r < need3) selKey[b * PRE_K + cgt + r] = my;
  }
}

// ---------------- rank-by-count ordering + candidate record emit -----------
__global__ __launch_bounds__(512) void k_rank(const u64* __restrict__ selKey,
                                              const u8* __restrict__ cats,
                                              const float* __restrict__ boxes,
                                              float4* __restrict__ candOff,
                                              float4* __restrict__ candOrig,
                                              float* __restrict__ candScore,
                                              int* __restrict__ candCat) {
  int b = blockIdx.y;
  int tid = threadIdx.x;
  __shared__ u64 sk[PRE_K];  // 16 KB
  for (int i = tid; i < PRE_K; i += 512) sk[i] = selKey[b * PRE_K + i];
  __syncthreads();
  int me = blockIdx.x * 512 + tid;
  u64 my = sk[me];
  int rank = 0;
  #pragma unroll 8
  for (int j = 0; j < PRE_K; ++j) rank += (sk[j] > my);
  u32 n = 0xFFFFFFFFu - (u32)(my & 0xFFFFFFFFu);
  float s = sort2f((u32)(my >> 32));
  int cat = (int)cats[(size_t)b * NANCH + n];
  const float* bp = boxes + ((size_t)b * NANCH + n) * 4;
  float4 ob = make_float4(bp[0], bp[1], bp[2], bp[3]);
  float off = 2.0f * (float)cat;
  float4 obo = make_float4(ob.x + off, ob.y + off, ob.z + off, ob.w + off);
  int o = b * PRE_K + rank;
  candOff[o] = obo;
  candOrig[o] = ob;
  candScore[o] = s;
  candCat[o] = cat;
}

// ---------------- 2048x2048 upper-triangle suppression bitmask -------------
// one wave per row; lane l handles column c*64+l (conflict-free b128 reads);
// word built by __ballot, parked in lane c; coalesced 32x8B store per row.
__global__ __launch_bounds__(256) void k_mask(const float4* __restrict__ candOff,
                                              u64* __restrict__ mask) {
  int b = blockIdx.y;
  int tid = threadIdx.x;
  int wave = tid >> 6, lane = tid & 63;
  __shared__ float4 sb[PRE_K];   // 32 KB
  __shared__ float sarea[PRE_K]; // 8 KB
  for (int j = tid; j < PRE_K; j += 256) {
    float4 v = candOff[b * PRE_K + j];
    sb[j] = v;
    sarea[j] = fmaxf(v.z - v.x, 0.0f) * fmaxf(v.w - v.y, 0.0f);
  }
  __syncthreads();

  int gw = blockIdx.x * 4 + wave;  // 0..255 per batch
  for (int k = 0; k < PRE_K / 256; ++k) {
    int i = gw + 256 * k;
    float4 bi = sb[i];           // LDS broadcast
    float ai = sarea[i];
    int c0 = i >> 6;
    u64 myword = 0;
    for (int c = c0; c < 32; ++c) {
      float4 bj = sb[c * 64 + lane];
      float aj = sarea[c * 64 + lane];
      float lx = fmaxf(bi.x, bj.x), ly = fmaxf(bi.y, bj.y);
      float rx = fminf(bi.z, bj.z), ry = fminf(bi.w, bj.w);
      float iw = fmaxf(rx - lx, 0.0f), ih = fmaxf(ry - ly, 0.0f);
      float inter = iw * ih;
      float uni = fmaxf(ai + aj - inter, 1e-9f);
      // iou > 0.5  <=>  inter > 0.5*uni  (uni >= max area > 2e-5 here)
      u64 word = __ballot(inter > 0.5f * uni);
      if (lane == c) myword = word;
    }
    if (lane < 32) mask[((size_t)(b * PRE_K + i)) * 32 + lane] = myword;
  }
}

// ---------------- greedy scan + output -------------------------------------
__global__ __launch_bounds__(64) void k_scan(const u64* __restrict__ mask,
                                             const float4* __restrict__ candOrig,
                                             const float* __restrict__ candScore,
                                             const int* __restrict__ candCat,
                                             float* __restrict__ out) {
  int b = blockIdx.x;
  int tid = threadIdx.x;
  __shared__ float ssc[PRE_K];
  __shared__ int keptI[MAX_OUT];
  for (int j = tid; j < PRE_K; j += 64) ssc[j] = candScore[b * PRE_K + j];
  __syncthreads();

  const u64* mrow = mask + (size_t)b * PRE_K * 32;
  int wsel = tid & 31;
  u64 remv = 0;
  int cnt = 0;
  u64 rowCur = mrow[wsel];
  for (int i = 0; i < PRE_K && cnt < MAX_OUT; ++i) {
    u64 rowNxt = (i + 1 < PRE_K) ? mrow[(size_t)(i + 1) * 32 + wsel] : 0ull;
    u64 wbits = __shfl(remv, i >> 6);
    bool sup = (wbits >> (i & 63)) & 1ull;
    if (!sup && ssc[i] > SCORE_TH) {
      if (tid == 0) keptI[cnt] = i;
      if (tid < 32) remv |= rowCur;
      cnt++;
    }
    rowCur = rowNxt;
  }
  __syncthreads();

  float* out5 = out;
  float* ocat = out + BATCH * MAX_OUT * 5;
  for (int r = tid; r < MAX_OUT; r += 64) {
    float* p = out5 + ((size_t)(b * MAX_OUT + r)) * 5;
    if (r < cnt) {
      int i = keptI[r];
      float4 ob = candOrig[b * PRE_K + i];
      p[0] = ob.x; p[1] = ob.y; p[2] = ob.z; p[3] = ob.w; p[4] = ssc[i];
      ocat[b * MAX_OUT + r] = (float)candCat[b * PRE_K + i];
    } else {
      p[0] = 0.0f; p[1] = 0.0f; p[2] = 0.0f; p[3] = 0.0f; p[4] = 0.0f;
      ocat[b * MAX_OUT + r] = 0.0f;
    }
  }
}

extern "C" void kernel_launch(void* const* d_in, const int* in_sizes, int n_in,
                              void* d_out, int out_size, void* d_ws, size_t ws_size,
                              hipStream_t stream) {
  const float* boxes = (const float*)d_in[0];
  const float* confs = (const float*)d_in[1];
  float* out = (float*)d_out;
  char* ws = (char*)d_ws;

  const size_t OFF_KEYS = 0;                            // 2 MB
  const size_t OFF_CATS = (size_t)2 << 20;              // 256 KB (u8)
  const size_t OFF_H1   = OFF_CATS + (256u << 10);      // 8 KB
  const size_t OFF_H2   = OFF_H1 + 8 * 256 * 4;         // 64 KB
  const size_t OFF_H3   = OFF_H2 + 8 * 2048 * 4;        // 256 KB
  const size_t OFF_CNT  = OFF_H3 + 8 * 8192 * 4;        // 1 KB
  const size_t OFF_SELK = OFF_CNT + 1024;               // 128 KB
  const size_t OFF_TIE  = OFF_SELK + 8 * PRE_K * 8;     // 8 KB
  const size_t OFF_COFF = OFF_TIE + 8 * 128 * 8;        // 256 KB
  const size_t OFF_CORG = OFF_COFF + (256u << 10);      // 256 KB
  const size_t OFF_CSC  = OFF_CORG + (256u << 10);      // 64 KB
  const size_t OFF_CCAT = OFF_CSC + (64u << 10);        // 64 KB
  const size_t OFF_MASK = OFF_CCAT + (64u << 10);       // 4 MB

  u64* keys    = (u64*)(ws + OFF_KEYS);
  u8* cats     = (u8*)(ws + OFF_CATS);
  u32* h1      = (u32*)(ws + OFF_H1);
  u32* h2      = (u32*)(ws + OFF_H2);
  u32* h3      = (u32*)(ws + OFF_H3);
  u32* cntSel  = (u32*)(ws + OFF_CNT);
  u32* cntTie  = (u32*)(ws + OFF_CNT + 64);
  u32* gNeed3  = (u32*)(ws + OFF_CNT + 128);
  u64* selKey  = (u64*)(ws + OFF_SELK);
  u64* tieKey  = (u64*)(ws + OFF_TIE);
  float4* cOff = (float4*)(ws + OFF_COFF);
  float4* cOrg = (float4*)(ws + OFF_CORG);
  float* cSc   = (float*)(ws + OFF_CSC);
  int* cCat    = (int*)(ws + OFF_CCAT);
  u64* mask    = (u64*)(ws + OFF_MASK);

  hipMemsetAsync(ws + OFF_H1, 0, (OFF_CNT + 1024) - OFF_H1, stream);

  k_score<<<BATCH * NANCH / 4, 256, 0, stream>>>(confs, keys, cats);
  k_hist1<<<32, 1024, 0, stream>>>(keys, h1);
  k_hist2<<<32, 1024, 0, stream>>>(keys, h1, h2);
  k_hist3<<<32, 1024, 0, stream>>>(keys, h1, h2, h3);
  k_compact<<<32, 1024, 0, stream>>>(keys, h1, h2, h3, selKey, tieKey, cntSel, cntTie, gNeed3);
  k_resolve<<<BATCH, 256, 0, stream>>>(selKey, tieKey, cntSel, cntTie, gNeed3);
  dim3 gr(PRE_K / 512, BATCH);
  k_rank<<<gr, 512, 0, stream>>>(selKey, cats, boxes, cOff, cOrg, cSc, cCat);
  dim3 g3(64, BATCH);
  k_mask<<<g3, 256, 0, stream>>>(cOff, mask);
  k_scan<<<BATCH, 64, 0, stream>>>(mask, cOrg, cSc, cCat, out);
}

// Round 4
// 203.619 us; speedup vs baseline: 1.5273x; 1.1838x over previous
//
#include <hip/hip_runtime.h>
#include <stdint.h>

#define BATCH 8
#define NANCH 32768
#define NCLS 81
#define PRE_K 2048
#define MAX_OUT 200
#define IOU_TH 0.5f
#define SCORE_TH 0.05f

typedef uint32_t u32;
typedef uint64_t u64;
typedef uint8_t u8;

// monotone float->u32 (order-preserving)
__device__ __forceinline__ u32 f2sort(float f) {
  u32 u = __float_as_uint(f);
  return (u & 0x80000000u) ? ~u : (u | 0x80000000u);
}
__device__ __forceinline__ float sort2f(u32 u) {
  u = (u & 0x80000000u) ? (u & 0x7FFFFFFFu) : ~u;
  return __uint_as_float(u);
}

// ---------------- kernel 1: per-anchor max/argmax over 81 classes ----------
// 16 lanes per anchor, 4 anchors per wave. Key = (bits(v)<<7)|(127-c):
// conf in [0,1) => positive => raw bits monotone; max key = max val,
// tie -> smallest class index (first-max, matches jnp.argmax).
__global__ __launch_bounds__(256) void k_score(const float* __restrict__ confs,
                                               u64* __restrict__ keys,
                                               u8* __restrict__ cats) {
  int w = blockIdx.x * 4 + (threadIdx.x >> 6);  // wave id, 4096 total
  int lane = threadIdx.x & 63;
  int g = lane >> 4, sub = lane & 15;
  int base = w * 64;  // 64 anchors per wave

  for (int it = 0; it < 16; ++it) {
    int a = base + it * 4 + g;                   // this group's anchor
    const float* p = confs + (size_t)a * NCLS;
    // serial max over c = sub, sub+16, sub+32, sub+48, sub+64 (+80 for sub==0)
    float v0 = p[sub];
    u64 key = ((u64)__float_as_uint(v0) << 7) | (u32)(127 - sub);
    #pragma unroll
    for (int k = 1; k < 5; ++k) {
      int c = sub + 16 * k;
      float v = p[c];
      u64 k2 = ((u64)__float_as_uint(v) << 7) | (u32)(127 - c);
      if (k2 > key) key = k2;
    }
    if (sub == 0) {
      float v = p[80];
      u64 k2 = ((u64)__float_as_uint(v) << 7) | (u32)(127 - 80);
      if (k2 > key) key = k2;
    }
    // 4-stage butterfly within the 16-lane group
    #pragma unroll
    for (int off = 8; off; off >>= 1) {
      u64 o = __shfl_xor(key, off);
      if (o > key) key = o;
    }
    if (sub == 0) {
      float v = __uint_as_float((u32)(key >> 7));
      int c = 127 - (int)(key & 127);
      int n = a & (NANCH - 1);
      bool valid = (v > SCORE_TH) && (c != 0);
      float s = valid ? v : -1.0f;
      keys[a] = ((u64)f2sort(s) << 32) | (u64)(0xFFFFFFFFu - (u32)n);
      cats[a] = (u8)c;
    }
  }
}

// ------------- digit-threshold scan helper (redundant per WG) --------------
template <int B>
__device__ void scan_digit(const u32* __restrict__ gh, int need, u32* sbuf,
                           int tid, int* D, int* NO) {
  const int CS = B / 256;
  u32 psum = 0;
  if (tid < 256) {
    int hi = B - 1 - tid * CS;
    #pragma unroll 4
    for (int k2 = 0; k2 < CS; ++k2) psum += gh[hi - k2];
    sbuf[tid] = psum;
  }
  __syncthreads();
  for (int off = 1; off < 256; off <<= 1) {
    u32 v = 0;
    if (tid < 256 && tid >= off) v = sbuf[tid - off];
    __syncthreads();
    if (tid < 256) sbuf[tid] += v;
    __syncthreads();
  }
  if (tid < 256) {
    u32 inc = sbuf[tid], exc = inc - psum;
    if (inc >= (u32)need && exc < (u32)need) {
      int acc = (int)exc, hi = B - 1 - tid * CS, d = hi, no = 0;
      for (int k2 = 0; k2 < CS; ++k2) {
        d = hi - k2;
        u32 h = gh[d];
        acc += (int)h;
        if (acc >= need) { no = need - (acc - (int)h); break; }
      }
      sbuf[256] = (u32)d;
      sbuf[257] = (u32)no;
    }
  }
  __syncthreads();
  *D = (int)sbuf[256];
  *NO = (int)sbuf[257];
  __syncthreads();
}

// ---------------- histogram passes (grid-parallel, 4 WGs/batch) ------------
__global__ __launch_bounds__(1024) void k_hist1(const u64* __restrict__ keys,
                                                u32* __restrict__ h1) {
  int b = blockIdx.x >> 2, sub = blockIdx.x & 3;
  __shared__ u32 lh[256];
  for (int i = threadIdx.x; i < 256; i += 1024) lh[i] = 0;
  __syncthreads();
  const u64* bk = keys + (size_t)b * NANCH;
  int base = sub * 8192;
  for (int i = base + threadIdx.x; i < base + 8192; i += 1024) {
    u32 k32 = (u32)(bk[i] >> 32);
    atomicAdd(&lh[k32 >> 24], 1u);
  }
  __syncthreads();
  for (int i = threadIdx.x; i < 256; i += 1024) {
    u32 v = lh[i];
    if (v) atomicAdd(&h1[b * 256 + i], v);
  }
}

__global__ __launch_bounds__(1024) void k_hist2(const u64* __restrict__ keys,
                                                const u32* __restrict__ h1,
                                                u32* __restrict__ h2) {
  int b = blockIdx.x >> 2, sub = blockIdx.x & 3;
  __shared__ u32 sbuf[258];
  __shared__ u32 lh[2048];
  int D1, n1;
  scan_digit<256>(h1 + b * 256, PRE_K, sbuf, threadIdx.x, &D1, &n1);
  for (int i = threadIdx.x; i < 2048; i += 1024) lh[i] = 0;
  __syncthreads();
  const u64* bk = keys + (size_t)b * NANCH;
  int base = sub * 8192;
  for (int i = base + threadIdx.x; i < base + 8192; i += 1024) {
    u32 k32 = (u32)(bk[i] >> 32);
    if ((int)(k32 >> 24) == D1) atomicAdd(&lh[(k32 >> 13) & 0x7FF], 1u);
  }
  __syncthreads();
  for (int i = threadIdx.x; i < 2048; i += 1024) {
    u32 v = lh[i];
    if (v) atomicAdd(&h2[b * 2048 + i], v);
  }
}

__global__ __launch_bounds__(1024) void k_hist3(const u64* __restrict__ keys,
                                                const u32* __restrict__ h1,
                                                const u32* __restrict__ h2,
                                                u32* __restrict__ h3) {
  int b = blockIdx.x >> 2, sub = blockIdx.x & 3;
  __shared__ u32 sbuf[258];
  __shared__ u32 lh[8192];  // 32 KB
  int D1, n1, D2, n2;
  scan_digit<256>(h1 + b * 256, PRE_K, sbuf, threadIdx.x, &D1, &n1);
  scan_digit<2048>(h2 + b * 2048, n1, sbuf, threadIdx.x, &D2, &n2);
  for (int i = threadIdx.x; i < 8192; i += 1024) lh[i] = 0;
  __syncthreads();
  const u64* bk = keys + (size_t)b * NANCH;
  int base = sub * 8192;
  for (int i = base + threadIdx.x; i < base + 8192; i += 1024) {
    u32 k32 = (u32)(bk[i] >> 32);
    if ((int)(k32 >> 24) == D1 && (int)((k32 >> 13) & 0x7FF) == D2)
      atomicAdd(&lh[k32 & 0x1FFF], 1u);
  }
  __syncthreads();
  for (int i = threadIdx.x; i < 8192; i += 1024) {
    u32 v = lh[i];
    if (v) atomicAdd(&h3[b * 8192 + i], v);
  }
}

// ---------------- compaction: strict-greater + boundary ties ---------------
__global__ __launch_bounds__(1024) void k_compact(const u64* __restrict__ keys,
                                                  const u32* __restrict__ h1,
                                                  const u32* __restrict__ h2,
                                                  const u32* __restrict__ h3,
                                                  u64* __restrict__ selKey,
                                                  u64* __restrict__ tieKey,
                                                  u32* __restrict__ cntSel,
                                                  u32* __restrict__ cntTie,
                                                  u32* __restrict__ gNeed3) {
  int b = blockIdx.x >> 2, sub = blockIdx.x & 3;
  __shared__ u32 sbuf[258];
  int D1, n1, D2, n2, D3, n3;
  scan_digit<256>(h1 + b * 256, PRE_K, sbuf, threadIdx.x, &D1, &n1);
  scan_digit<2048>(h2 + b * 2048, n1, sbuf, threadIdx.x, &D2, &n2);
  scan_digit<8192>(h3 + b * 8192, n2, sbuf, threadIdx.x, &D3, &n3);
  u32 S32 = ((u32)D1 << 24) | ((u32)D2 << 13) | (u32)D3;
  if (threadIdx.x == 0 && sub == 0) gNeed3[b] = (u32)n3;
  const u64* bk = keys + (size_t)b * NANCH;
  int base = sub * 8192;
  for (int i = base + threadIdx.x; i < base + 8192; i += 1024) {
    u64 k = bk[i];
    u32 k32 = (u32)(k >> 32);
    if (k32 > S32) {
      u32 pos = atomicAdd(&cntSel[b], 1u);
      selKey[b * PRE_K + pos] = k;
    } else if (k32 == S32) {
      u32 pos = atomicAdd(&cntTie[b], 1u);
      if (pos < 128) tieKey[b * 128 + pos] = k;
    }
  }
}

// resolve boundary ties: take need3 largest keys (== smallest anchor index)
__global__ __launch_bounds__(256) void k_resolve(u64* __restrict__ selKey,
                                                 const u64* __restrict__ tieKey,
                                                 const u32* __restrict__ cntSel,
                                                 const u32* __restrict__ cntTie,
                                                 const u32* __restrict__ gNeed3) {
  int b = blockIdx.x;
  int nt = (int)cntTie[b];
  if (nt > 128) nt = 128;
  int need3 = (int)gNeed3[b];
  int cgt = (int)cntSel[b];
  int t = threadIdx.x;
  if (t < nt) {
    u64 my = tieKey[b * 128 + t];
    int r = 0;
    for (int j = 0; j < nt; ++j) r += (tieKey[b * 128 + j] > my);
    if (r < need3) selKey[b * PRE_K + cgt + r] = my;
  }
}

// ---------------- rank-by-count ordering + candidate record emit -----------
__global__ __launch_bounds__(512) void k_rank(const u64* __restrict__ selKey,
                                              const u8* __restrict__ cats,
                                              const float* __restrict__ boxes,
                                              float4* __restrict__ candOff,
                                              float4* __restrict__ candOrig,
                                              float* __restrict__ candScore,
                                              int* __restrict__ candCat) {
  int b = blockIdx.y;
  int tid = threadIdx.x;
  __shared__ u64 sk[PRE_K];  // 16 KB
  for (int i = tid; i < PRE_K; i += 512) sk[i] = selKey[b * PRE_K + i];
  __syncthreads();
  int me = blockIdx.x * 512 + tid;
  u64 my = sk[me];
  int rank = 0;
  #pragma unroll 8
  for (int j = 0; j < PRE_K; ++j) rank += (sk[j] > my);
  u32 n = 0xFFFFFFFFu - (u32)(my & 0xFFFFFFFFu);
  float s = sort2f((u32)(my >> 32));
  int cat = (int)cats[(size_t)b * NANCH + n];
  const float* bp = boxes + ((size_t)b * NANCH + n) * 4;
  float4 ob = make_float4(bp[0], bp[1], bp[2], bp[3]);
  float off = 2.0f * (float)cat;
  float4 obo = make_float4(ob.x + off, ob.y + off, ob.z + off, ob.w + off);
  int o = b * PRE_K + rank;
  candOff[o] = obo;
  candOrig[o] = ob;
  candScore[o] = s;
  candCat[o] = cat;
}

// ---------------- 2048x2048 upper-triangle suppression bitmask -------------
__global__ __launch_bounds__(256) void k_mask(const float4* __restrict__ candOff,
                                              u64* __restrict__ mask) {
  int b = blockIdx.y;
  int tid = threadIdx.x;
  int wave = tid >> 6, lane = tid & 63;
  __shared__ float4 sb[PRE_K];   // 32 KB
  __shared__ float sarea[PRE_K]; // 8 KB
  for (int j = tid; j < PRE_K; j += 256) {
    float4 v = candOff[b * PRE_K + j];
    sb[j] = v;
    sarea[j] = fmaxf(v.z - v.x, 0.0f) * fmaxf(v.w - v.y, 0.0f);
  }
  __syncthreads();

  int gw = blockIdx.x * 4 + wave;
  for (int k = 0; k < PRE_K / 256; ++k) {
    int i = gw + 256 * k;
    float4 bi = sb[i];
    float ai = sarea[i];
    int c0 = i >> 6;
    u64 myword = 0;
    for (int c = c0; c < 32; ++c) {
      float4 bj = sb[c * 64 + lane];
      float aj = sarea[c * 64 + lane];
      float lx = fmaxf(bi.x, bj.x), ly = fmaxf(bi.y, bj.y);
      float rx = fminf(bi.z, bj.z), ry = fminf(bi.w, bj.w);
      float iw = fmaxf(rx - lx, 0.0f), ih = fmaxf(ry - ly, 0.0f);
      float inter = iw * ih;
      float uni = fmaxf(ai + aj - inter, 1e-9f);
      u64 word = __ballot(inter > 0.5f * uni);
      if (lane == c) myword = word;
    }
    if (lane < 32) mask[((size_t)(b * PRE_K + i)) * 32 + lane] = myword;
  }
}

// ---------------- greedy scan + output (8-deep row prefetch) ---------------
__global__ __launch_bounds__(64) void k_scan(const u64* __restrict__ mask,
                                             const float4* __restrict__ candOrig,
                                             const float* __restrict__ candScore,
                                             const int* __restrict__ candCat,
                                             float* __restrict__ out) {
  int b = blockIdx.x;
  int tid = threadIdx.x;
  __shared__ float ssc[PRE_K];
  __shared__ int keptI[MAX_OUT];
  for (int j = tid; j < PRE_K; j += 64) ssc[j] = candScore[b * PRE_K + j];
  __syncthreads();

  const u64* mrow = mask + (size_t)b * PRE_K * 32;
  int wsel = tid & 31;
  bool lo32 = tid < 32;
  u64 remv = 0;
  int cnt = 0;

  u64 c0=0,c1=0,c2=0,c3=0,c4=0,c5=0,c6=0,c7=0;
  if (lo32) {
    c0 = mrow[0 * 32 + wsel]; c1 = mrow[1 * 32 + wsel];
    c2 = mrow[2 * 32 + wsel]; c3 = mrow[3 * 32 + wsel];
    c4 = mrow[4 * 32 + wsel]; c5 = mrow[5 * 32 + wsel];
    c6 = mrow[6 * 32 + wsel]; c7 = mrow[7 * 32 + wsel];
  }

#define PROCESS(I, RK)                                   \
  {                                                      \
    u64 wb = __shfl(remv, (I) >> 6);                     \
    bool sup = (wb >> ((I) & 63)) & 1ull;                \
    if (!sup && ssc[I] > SCORE_TH) {                     \
      if (tid == 0 && cnt < MAX_OUT) keptI[cnt] = (I);   \
      if (lo32) remv |= (RK);                            \
      cnt++;                                             \
    }                                                    \
  }

  for (int base = 0; base < PRE_K; base += 8) {
    u64 n0=0,n1=0,n2=0,n3=0,n4=0,n5=0,n6=0,n7=0;
    if (base + 8 < PRE_K && lo32) {
      const u64* nr = mrow + (size_t)(base + 8) * 32 + wsel;
      n0 = nr[0 * 32]; n1 = nr[1 * 32]; n2 = nr[2 * 32]; n3 = nr[3 * 32];
      n4 = nr[4 * 32]; n5 = nr[5 * 32]; n6 = nr[6 * 32]; n7 = nr[7 * 32];
    }
    PROCESS(base + 0, c0); PROCESS(base + 1, c1);
    PROCESS(base + 2, c2); PROCESS(base + 3, c3);
    PROCESS(base + 4, c4); PROCESS(base + 5, c5);
    PROCESS(base + 6, c6); PROCESS(base + 7, c7);
    c0=n0; c1=n1; c2=n2; c3=n3; c4=n4; c5=n5; c6=n6; c7=n7;
    if (cnt >= MAX_OUT) break;
  }
#undef PROCESS

  int kc = cnt < MAX_OUT ? cnt : MAX_OUT;
  __syncthreads();

  float* out5 = out;
  float* ocat = out + BATCH * MAX_OUT * 5;
  for (int r = tid; r < MAX_OUT; r += 64) {
    float* p = out5 + ((size_t)(b * MAX_OUT + r)) * 5;
    if (r < kc) {
      int i = keptI[r];
      float4 ob = candOrig[b * PRE_K + i];
      p[0] = ob.x; p[1] = ob.y; p[2] = ob.z; p[3] = ob.w; p[4] = ssc[i];
      ocat[b * MAX_OUT + r] = (float)candCat[b * PRE_K + i];
    } else {
      p[0] = 0.0f; p[1] = 0.0f; p[2] = 0.0f; p[3] = 0.0f; p[4] = 0.0f;
      ocat[b * MAX_OUT + r] = 0.0f;
    }
  }
}

extern "C" void kernel_launch(void* const* d_in, const int* in_sizes, int n_in,
                              void* d_out, int out_size, void* d_ws, size_t ws_size,
                              hipStream_t stream) {
  const float* boxes = (const float*)d_in[0];
  const float* confs = (const float*)d_in[1];
  float* out = (float*)d_out;
  char* ws = (char*)d_ws;

  const size_t OFF_KEYS = 0;                            // 2 MB
  const size_t OFF_CATS = (size_t)2 << 20;              // 256 KB (u8)
  const size_t OFF_H1   = OFF_CATS + (256u << 10);      // 8 KB
  const size_t OFF_H2   = OFF_H1 + 8 * 256 * 4;         // 64 KB
  const size_t OFF_H3   = OFF_H2 + 8 * 2048 * 4;        // 256 KB
  const size_t OFF_CNT  = OFF_H3 + 8 * 8192 * 4;        // 1 KB
  const size_t OFF_SELK = OFF_CNT + 1024;               // 128 KB
  const size_t OFF_TIE  = OFF_SELK + 8 * PRE_K * 8;     // 8 KB
  const size_t OFF_COFF = OFF_TIE + 8 * 128 * 8;        // 256 KB
  const size_t OFF_CORG = OFF_COFF + (256u << 10);      // 256 KB
  const size_t OFF_CSC  = OFF_CORG + (256u << 10);      // 64 KB
  const size_t OFF_CCAT = OFF_CSC + (64u << 10);        // 64 KB
  const size_t OFF_MASK = OFF_CCAT + (64u << 10);       // 4 MB

  u64* keys    = (u64*)(ws + OFF_KEYS);
  u8* cats     = (u8*)(ws + OFF_CATS);
  u32* h1      = (u32*)(ws + OFF_H1);
  u32* h2      = (u32*)(ws + OFF_H2);
  u32* h3      = (u32*)(ws + OFF_H3);
  u32* cntSel  = (u32*)(ws + OFF_CNT);
  u32* cntTie  = (u32*)(ws + OFF_CNT + 64);
  u32* gNeed3  = (u32*)(ws + OFF_CNT + 128);
  u64* selKey  = (u64*)(ws + OFF_SELK);
  u64* tieKey  = (u64*)(ws + OFF_TIE);
  float4* cOff = (float4*)(ws + OFF_COFF);
  float4* cOrg = (float4*)(ws + OFF_CORG);
  float* cSc   = (float*)(ws + OFF_CSC);
  int* cCat    = (int*)(ws + OFF_CCAT);
  u64* mask    = (u64*)(ws + OFF_MASK);

  hipMemsetAsync(ws + OFF_H1, 0, (OFF_CNT + 1024) - OFF_H1, stream);

  k_score<<<1024, 256, 0, stream>>>(confs, keys, cats);
  k_hist1<<<32, 1024, 0, stream>>>(keys, h1);
  k_hist2<<<32, 1024, 0, stream>>>(keys, h1, h2);
  k_hist3<<<32, 1024, 0, stream>>>(keys, h1, h2, h3);
  k_compact<<<32, 1024, 0, stream>>>(keys, h1, h2, h3, selKey, tieKey, cntSel, cntTie, gNeed3);
  k_resolve<<<BATCH, 256, 0, stream>>>(selKey, tieKey, cntSel, cntTie, gNeed3);
  dim3 gr(PRE_K / 512, BATCH);
  k_rank<<<gr, 512, 0, stream>>>(selKey, cats, boxes, cOff, cOrg, cSc, cCat);
  dim3 g3(64, BATCH);
  k_mask<<<g3, 256, 0, stream>>>(cOff, mask);
  k_scan<<<BATCH, 64, 0, stream>>>(mask, cOrg, cSc, cCat, out);
}

// Round 5
// 159.681 us; speedup vs baseline: 1.9476x; 1.2752x over previous
//
#include <hip/hip_runtime.h>
#include <stdint.h>

#define BATCH 8
#define NANCH 32768
#define NCLS 81
#define PRE_K 2048
#define MAX_OUT 200
#define IOU_TH 0.5f
#define SCORE_TH 0.05f

typedef uint32_t u32;
typedef uint64_t u64;
typedef uint8_t u8;

// monotone float->u32 (order-preserving)
__device__ __forceinline__ u32 f2sort(float f) {
  u32 u = __float_as_uint(f);
  return (u & 0x80000000u) ? ~u : (u | 0x80000000u);
}
__device__ __forceinline__ float sort2f(u32 u) {
  u = (u & 0x80000000u) ? (u & 0x7FFFFFFFu) : ~u;
  return __uint_as_float(u);
}

// ---------------- kernel 1: per-anchor max/argmax over 81 classes ----------
// Block = 64-anchor tile. Stage 1296 float4 -> LDS (streaming, high ILP),
// then 4 threads/anchor reduce 20-21 elems. Key=(bits(v)<<7)|(127-c):
// conf in [0,1) => bits monotone; tie -> smallest class (first-max).
__global__ __launch_bounds__(256) void k_score(const float* __restrict__ confs,
                                               u64* __restrict__ keys,
                                               u8* __restrict__ cats) {
  __shared__ float st[64 * NCLS];  // 20.25 KB
  __shared__ u64 outk[64];
  __shared__ u8 outc[64];
  int tid = threadIdx.x;
  const float4* src = (const float4*)confs + (size_t)blockIdx.x * (64 * NCLS / 4);
  float4* dst = (float4*)st;
  for (int idx = tid; idx < 64 * NCLS / 4; idx += 256) dst[idx] = src[idx];
  __syncthreads();

  int a = tid >> 2, s = tid & 3;
  const float* row = st + a * NCLS;
  int c0 = s * 20;
  int cnt = (s == 3) ? 21 : 20;  // slots cover 0..59 / 60..80
  u64 key = 0;
  for (int k = 0; k < cnt; ++k) {
    int c = c0 + k;
    u64 k2 = ((u64)__float_as_uint(row[c]) << 7) | (u32)(127 - c);
    if (k2 > key) key = k2;
  }
  u64 o = __shfl_xor(key, 1); if (o > key) key = o;
  o = __shfl_xor(key, 2); if (o > key) key = o;
  if (s == 0) {
    float v = __uint_as_float((u32)(key >> 7));
    int c = 127 - (int)(key & 127);
    int n = (blockIdx.x * 64 + a) & (NANCH - 1);
    bool valid = (v > SCORE_TH) && (c != 0);
    float sc = valid ? v : -1.0f;
    outk[a] = ((u64)f2sort(sc) << 32) | (u64)(0xFFFFFFFFu - (u32)n);
    outc[a] = (u8)c;
  }
  __syncthreads();
  if (tid < 64) {
    int g = blockIdx.x * 64 + tid;
    keys[g] = outk[tid];
    cats[g] = outc[tid];
  }
}

// ------------- digit-threshold scan helper (LDS hist) ----------------------
template <int B>
__device__ void scan_digit(const u32* gh, int need, u32* sbuf,
                           int tid, int* D, int* NO) {
  const int CS = B / 256;
  u32 psum = 0;
  if (tid < 256) {
    int hi = B - 1 - tid * CS;
    #pragma unroll 4
    for (int k2 = 0; k2 < CS; ++k2) psum += gh[hi - k2];
    sbuf[tid] = psum;
  }
  __syncthreads();
  for (int off = 1; off < 256; off <<= 1) {
    u32 v = 0;
    if (tid < 256 && tid >= off) v = sbuf[tid - off];
    __syncthreads();
    if (tid < 256) sbuf[tid] += v;
    __syncthreads();
  }
  if (tid < 256) {
    u32 inc = sbuf[tid], exc = inc - psum;
    if (inc >= (u32)need && exc < (u32)need) {
      int acc = (int)exc, hi = B - 1 - tid * CS, d = hi, no = 0;
      for (int k2 = 0; k2 < CS; ++k2) {
        d = hi - k2;
        u32 h = gh[d];
        acc += (int)h;
        if (acc >= need) { no = need - (acc - (int)h); break; }
      }
      sbuf[256] = (u32)d;
      sbuf[257] = (u32)no;
    }
  }
  __syncthreads();
  *D = (int)sbuf[256];
  *NO = (int)sbuf[257];
  __syncthreads();
}

// ---------------- kernel 2: exact 32-bit threshold, 1 WG/batch -------------
// Keys' high words held in 32 VGPRs; 8/12/12-bit LDS hist passes.
__global__ __launch_bounds__(1024) void k_thresh(const u64* __restrict__ keys,
                                                 u32* __restrict__ gS32,
                                                 u32* __restrict__ gNeed) {
  int b = blockIdx.x;
  int tid = threadIdx.x;
  __shared__ u32 hist[4096];  // 16 KB
  __shared__ u32 sbuf[258];
  const u64* bk = keys + (size_t)b * NANCH;
  u32 hk[32];
  #pragma unroll
  for (int i = 0; i < 32; ++i) hk[i] = (u32)(bk[tid + i * 1024] >> 32);

  // pass 1: top 8 bits
  for (int i = tid; i < 4096; i += 1024) hist[i] = 0;
  __syncthreads();
  #pragma unroll
  for (int i = 0; i < 32; ++i) atomicAdd(&hist[hk[i] >> 24], 1u);
  __syncthreads();
  int D1, n1;
  scan_digit<256>(hist, PRE_K, sbuf, tid, &D1, &n1);

  // pass 2: next 12 bits
  for (int i = tid; i < 4096; i += 1024) hist[i] = 0;
  __syncthreads();
  u32 p1 = (u32)D1;
  #pragma unroll
  for (int i = 0; i < 32; ++i)
    if ((hk[i] >> 24) == p1) atomicAdd(&hist[(hk[i] >> 12) & 0xFFF], 1u);
  __syncthreads();
  int D2, n2;
  scan_digit<4096>(hist, n1, sbuf, tid, &D2, &n2);

  // pass 3: low 12 bits
  for (int i = tid; i < 4096; i += 1024) hist[i] = 0;
  __syncthreads();
  u32 p2 = (p1 << 12) | (u32)D2;
  #pragma unroll
  for (int i = 0; i < 32; ++i)
    if ((hk[i] >> 12) == p2) atomicAdd(&hist[hk[i] & 0xFFF], 1u);
  __syncthreads();
  int D3, n3;
  scan_digit<4096>(hist, n2, sbuf, tid, &D3, &n3);

  if (tid == 0) {
    gS32[b] = (p2 << 12) | (u32)D3;
    gNeed[b] = (u32)n3;
  }
}

// ---------------- kernel 3: compact + tie-resolve, 1 WG/batch --------------
// Wave-aggregated LDS counter (ballot+popc), ties resolved in-WG.
__global__ __launch_bounds__(1024) void k_cmpres(const u64* __restrict__ keys,
                                                 const u32* __restrict__ gS32,
                                                 const u32* __restrict__ gNeed,
                                                 u64* __restrict__ selKey) {
  int b = blockIdx.x;
  int tid = threadIdx.x;
  int lane = tid & 63;
  __shared__ u32 s_cnt, s_tcnt;
  __shared__ u64 ties[128];
  if (tid == 0) { s_cnt = 0; s_tcnt = 0; }
  __syncthreads();
  u32 S32 = gS32[b];
  int need3 = (int)gNeed[b];
  const u64* bk = keys + (size_t)b * NANCH;
  u64* sel = selKey + (size_t)b * PRE_K;
  for (int i = tid; i < NANCH; i += 1024) {
    u64 k = bk[i];
    u32 k32 = (u32)(k >> 32);
    bool gt = k32 > S32;
    u64 m = __ballot(gt);
    u32 wbase = 0;
    if (lane == 0 && m) wbase = atomicAdd(&s_cnt, (u32)__popcll(m));
    wbase = __shfl(wbase, 0);
    if (gt) {
      int lr = __popcll(m & ((1ull << lane) - 1));
      sel[wbase + lr] = k;
    }
    if (k32 == S32) {
      u32 tp = atomicAdd(&s_tcnt, 1u);
      if (tp < 128) ties[tp] = k;
    }
  }
  __syncthreads();
  int nt = (int)s_tcnt; if (nt > 128) nt = 128;
  int base = (int)s_cnt;  // == PRE_K - need3
  if (tid < nt) {
    u64 my = ties[tid];
    int r = 0;
    for (int j = 0; j < nt; ++j) r += (ties[j] > my);
    if (r < need3) sel[base + r] = my;
  }
}

// ---------------- rank-by-count ordering + candidate record emit -----------
__global__ __launch_bounds__(512) void k_rank(const u64* __restrict__ selKey,
                                              const u8* __restrict__ cats,
                                              const float* __restrict__ boxes,
                                              float4* __restrict__ candOff,
                                              float4* __restrict__ candOrig,
                                              float* __restrict__ candScore,
                                              int* __restrict__ candCat) {
  int b = blockIdx.y;
  int tid = threadIdx.x;
  __shared__ u64 sk[PRE_K];  // 16 KB
  for (int i = tid; i < PRE_K; i += 512) sk[i] = selKey[b * PRE_K + i];
  __syncthreads();
  int me = blockIdx.x * 512 + tid;
  u64 my = sk[me];
  int rank = 0;
  #pragma unroll 8
  for (int j = 0; j < PRE_K; ++j) rank += (sk[j] > my);
  u32 n = 0xFFFFFFFFu - (u32)(my & 0xFFFFFFFFu);
  float s = sort2f((u32)(my >> 32));
  int cat = (int)cats[(size_t)b * NANCH + n];
  const float* bp = boxes + ((size_t)b * NANCH + n) * 4;
  float4 ob = make_float4(bp[0], bp[1], bp[2], bp[3]);
  float off = 2.0f * (float)cat;
  float4 obo = make_float4(ob.x + off, ob.y + off, ob.z + off, ob.w + off);
  int o = b * PRE_K + rank;
  candOff[o] = obo;
  candOrig[o] = ob;
  candScore[o] = s;
  candCat[o] = cat;
}

// ---------------- 2048x2048 upper-triangle suppression bitmask -------------
__global__ __launch_bounds__(256) void k_mask(const float4* __restrict__ candOff,
                                              u64* __restrict__ mask) {
  int b = blockIdx.y;
  int tid = threadIdx.x;
  int wave = tid >> 6, lane = tid & 63;
  __shared__ float4 sb[PRE_K];   // 32 KB
  __shared__ float sarea[PRE_K]; // 8 KB
  for (int j = tid; j < PRE_K; j += 256) {
    float4 v = candOff[b * PRE_K + j];
    sb[j] = v;
    sarea[j] = fmaxf(v.z - v.x, 0.0f) * fmaxf(v.w - v.y, 0.0f);
  }
  __syncthreads();

  int gw = blockIdx.x * 4 + wave;
  for (int k = 0; k < PRE_K / 256; ++k) {
    int i = gw + 256 * k;
    float4 bi = sb[i];
    float ai = sarea[i];
    int c0 = i >> 6;
    u64 myword = 0;
    for (int c = c0; c < 32; ++c) {
      float4 bj = sb[c * 64 + lane];
      float aj = sarea[c * 64 + lane];
      float lx = fmaxf(bi.x, bj.x), ly = fmaxf(bi.y, bj.y);
      float rx = fminf(bi.z, bj.z), ry = fminf(bi.w, bj.w);
      float iw = fmaxf(rx - lx, 0.0f), ih = fmaxf(ry - ly, 0.0f);
      float inter = iw * ih;
      float uni = fmaxf(ai + aj - inter, 1e-9f);
      u64 word = __ballot(inter > 0.5f * uni);
      if (lane == c) myword = word;
    }
    if (lane < 32) mask[((size_t)(b * PRE_K + i)) * 32 + lane] = myword;
  }
}

// ---------------- greedy scan + output (8-deep row prefetch) ---------------
__global__ __launch_bounds__(64) void k_scan(const u64* __restrict__ mask,
                                             const float4* __restrict__ candOrig,
                                             const float* __restrict__ candScore,
                                             const int* __restrict__ candCat,
                                             float* __restrict__ out) {
  int b = blockIdx.x;
  int tid = threadIdx.x;
  __shared__ float ssc[PRE_K];
  __shared__ int keptI[MAX_OUT];
  for (int j = tid; j < PRE_K; j += 64) ssc[j] = candScore[b * PRE_K + j];
  __syncthreads();

  const u64* mrow = mask + (size_t)b * PRE_K * 32;
  int wsel = tid & 31;
  bool lo32 = tid < 32;
  u64 remv = 0;
  int cnt = 0;

  u64 c0=0,c1=0,c2=0,c3=0,c4=0,c5=0,c6=0,c7=0;
  if (lo32) {
    c0 = mrow[0 * 32 + wsel]; c1 = mrow[1 * 32 + wsel];
    c2 = mrow[2 * 32 + wsel]; c3 = mrow[3 * 32 + wsel];
    c4 = mrow[4 * 32 + wsel]; c5 = mrow[5 * 32 + wsel];
    c6 = mrow[6 * 32 + wsel]; c7 = mrow[7 * 32 + wsel];
  }

#define PROCESS(I, RK)                                   \
  {                                                      \
    u64 wb = __shfl(remv, (I) >> 6);                     \
    bool sup = (wb >> ((I) & 63)) & 1ull;                \
    if (!sup && ssc[I] > SCORE_TH) {                     \
      if (tid == 0 && cnt < MAX_OUT) keptI[cnt] = (I);   \
      if (lo32) remv |= (RK);                            \
      cnt++;                                             \
    }                                                    \
  }

  for (int base = 0; base < PRE_K; base += 8) {
    u64 n0=0,n1=0,n2=0,n3=0,n4=0,n5=0,n6=0,n7=0;
    if (base + 8 < PRE_K && lo32) {
      const u64* nr = mrow + (size_t)(base + 8) * 32 + wsel;
      n0 = nr[0 * 32]; n1 = nr[1 * 32]; n2 = nr[2 * 32]; n3 = nr[3 * 32];
      n4 = nr[4 * 32]; n5 = nr[5 * 32]; n6 = nr[6 * 32]; n7 = nr[7 * 32];
    }
    PROCESS(base + 0, c0); PROCESS(base + 1, c1);
    PROCESS(base + 2, c2); PROCESS(base + 3, c3);
    PROCESS(base + 4, c4); PROCESS(base + 5, c5);
    PROCESS(base + 6, c6); PROCESS(base + 7, c7);
    c0=n0; c1=n1; c2=n2; c3=n3; c4=n4; c5=n5; c6=n6; c7=n7;
    if (cnt >= MAX_OUT) break;
  }
#undef PROCESS

  int kc = cnt < MAX_OUT ? cnt : MAX_OUT;
  __syncthreads();

  float* out5 = out;
  float* ocat = out + BATCH * MAX_OUT * 5;
  for (int r = tid; r < MAX_OUT; r += 64) {
    float* p = out5 + ((size_t)(b * MAX_OUT + r)) * 5;
    if (r < kc) {
      int i = keptI[r];
      float4 ob = candOrig[b * PRE_K + i];
      p[0] = ob.x; p[1] = ob.y; p[2] = ob.z; p[3] = ob.w; p[4] = ssc[i];
      ocat[b * MAX_OUT + r] = (float)candCat[b * PRE_K + i];
    } else {
      p[0] = 0.0f; p[1] = 0.0f; p[2] = 0.0f; p[3] = 0.0f; p[4] = 0.0f;
      ocat[b * MAX_OUT + r] = 0.0f;
    }
  }
}

extern "C" void kernel_launch(void* const* d_in, const int* in_sizes, int n_in,
                              void* d_out, int out_size, void* d_ws, size_t ws_size,
                              hipStream_t stream) {
  const float* boxes = (const float*)d_in[0];
  const float* confs = (const float*)d_in[1];
  float* out = (float*)d_out;
  char* ws = (char*)d_ws;

  const size_t OFF_KEYS = 0;                            // 2 MB
  const size_t OFF_CATS = (size_t)2 << 20;              // 256 KB (u8)
  const size_t OFF_THR  = OFF_CATS + (256u << 10);      // 64B S32 + 64B need
  const size_t OFF_SELK = OFF_THR + 128;                // 128 KB
  const size_t OFF_COFF = OFF_SELK + 8 * PRE_K * 8;     // 256 KB
  const size_t OFF_CORG = OFF_COFF + (256u << 10);      // 256 KB
  const size_t OFF_CSC  = OFF_CORG + (256u << 10);      // 64 KB
  const size_t OFF_CCAT = OFF_CSC + (64u << 10);        // 64 KB
  const size_t OFF_MASK = OFF_CCAT + (64u << 10);       // 4 MB

  u64* keys    = (u64*)(ws + OFF_KEYS);
  u8* cats     = (u8*)(ws + OFF_CATS);
  u32* gS32    = (u32*)(ws + OFF_THR);
  u32* gNeed   = (u32*)(ws + OFF_THR + 64);
  u64* selKey  = (u64*)(ws + OFF_SELK);
  float4* cOff = (float4*)(ws + OFF_COFF);
  float4* cOrg = (float4*)(ws + OFF_CORG);
  float* cSc   = (float*)(ws + OFF_CSC);
  int* cCat    = (int*)(ws + OFF_CCAT);
  u64* mask    = (u64*)(ws + OFF_MASK);

  k_score<<<BATCH * NANCH / 64, 256, 0, stream>>>(confs, keys, cats);
  k_thresh<<<BATCH, 1024, 0, stream>>>(keys, gS32, gNeed);
  k_cmpres<<<BATCH, 1024, 0, stream>>>(keys, gS32, gNeed, selKey);
  dim3 gr(PRE_K / 512, BATCH);
  k_rank<<<gr, 512, 0, stream>>>(selKey, cats, boxes, cOff, cOrg, cSc, cCat);
  dim3 g3(64, BATCH);
  k_mask<<<g3, 256, 0, stream>>>(cOff, mask);
  k_scan<<<BATCH, 64, 0, stream>>>(mask, cOrg, cSc, cCat, out);
}